// Round 8
// baseline (1012.775 us; speedup 1.0000x reference)
//
#include <hip/hip_runtime.h>
#include <math.h>

#define NTOT   32000      // total nodes
#define NNODE  2000       // nodes per graph
#define NB     16         // batch (graphs)
#define FIN    128        // input features
#define HCDIM  256        // heads*channels
#define NH     4          // heads
#define FC1DIM 512
#define FC2DIM 128
#define FCIN   12000      // 6*NNODE
#define NCH    250        // fc1 k-chunks
#define KCC    48         // fc1 k-rows per chunk (250*48 = 12000)
#define CAP    64         // padded adjacency capacity per node
#define BK     32
#define LPITCH 40         // LDS row pitch in bf16
#define TRB2   24         // tiled-transpose roles
#define DEMOB  375        // demo-fill roles
#define ZB     125        // cnt-zero roles
#define NBLK   512        // persistent grid: 2 blocks/CU x 256 CUs (launch_bounds(256,2))
#define SPIN_MAX 20000000 // barrier escape hatch: fail loud, not hung

typedef __attribute__((ext_vector_type(8))) short bf16x8;
typedef __attribute__((ext_vector_type(4))) float f32x4;

// ---------- small helpers ----------
__device__ inline float4 ld4(const float* p){ return *reinterpret_cast<const float4*>(p); }
__device__ inline float4 add4(float4 a, float4 b){ return make_float4(a.x+b.x,a.y+b.y,a.z+b.z,a.w+b.w); }
__device__ inline float lrelu(float x){ return x > 0.f ? x : 0.2f*x; }
__device__ inline float4 leaky4(float4 a){ return make_float4(lrelu(a.x),lrelu(a.y),lrelu(a.z),lrelu(a.w)); }
__device__ inline float4 exp4u(float4 a){ return make_float4(__expf(a.x),__expf(a.y),__expf(a.z),__expf(a.w)); }
__device__ inline float dot4(float4 a, float4 b){ return a.x*b.x + a.y*b.y + a.z*b.z + a.w*b.w; }
__device__ inline float selh(float4 v, int h){ return h==0 ? v.x : (h==1 ? v.y : (h==2 ? v.z : v.w)); }

__device__ inline unsigned short f2bf(float f){
  unsigned int u = __float_as_uint(f);
  u += 0x7FFFu + ((u >> 16) & 1u);
  return (unsigned short)(u >> 16);
}
__device__ inline unsigned int pk2bf(float a, float b){
  return (unsigned int)f2bf(a) | ((unsigned int)f2bf(b) << 16);
}
__device__ inline float bf2f(unsigned short h){
  return __uint_as_float(((unsigned int)h) << 16);
}
__device__ inline float4 ldbf4(const unsigned short* p){
  ushort4 v = *reinterpret_cast<const ushort4*>(p);
  return make_float4(bf2f(v.x), bf2f(v.y), bf2f(v.z), bf2f(v.w));
}

// ---------- parameter block ----------
struct MegaParams {
  const float *x, *W1, *attS1, *attD1, *b1;
  const float *W2, *attS2, *attD2, *b2;
  const float *pw1, *pb1, *pw2, *pb2;
  const float *lnw, *lnb, *sexemb, *mutemb, *agew, *ageb;
  const float *fw1, *fb1, *fw2, *fb2, *fw3, *fb3, *age;
  const int *esrc, *edst, *sex, *mut;
  float *out;
  float *a_s, *a_d, *x0r, *x1r, *x2r, *tbuf, *part, *t1;
  unsigned short *hA, *hB, *W1t, *W2t;
  int *cnt, *col;
  unsigned int *bar;
  int E0, eb;
};

// ---------- software grid barrier (all NBLK blocks co-resident by capacity) ----------
// Monotone counter: block at barrier i has old in [i*NBLK,(i+1)*NBLK) -> waits for
// (i+1)*NBLK. Agent-scope atomics + threadfence give cross-XCD release/acquire.
__device__ __forceinline__ void gridbar(unsigned int* bar){
  __syncthreads();
  if(threadIdx.x == 0){
    __threadfence();
    unsigned int old = __hip_atomic_fetch_add(bar, 1u, __ATOMIC_ACQ_REL, __HIP_MEMORY_SCOPE_AGENT);
    unsigned int target = (old/NBLK + 1u) * (unsigned int)NBLK;
    int guard = 0;
    while(__hip_atomic_load(bar, __ATOMIC_ACQUIRE, __HIP_MEMORY_SCOPE_AGENT) < target){
      if(++guard > SPIN_MAX) break;   // never triggers when co-resident
    }
    __threadfence();
  }
  __syncthreads();
}

// ---------- layernorm over one graph's 2000 values (one 256-thr block) ----------
__device__ __forceinline__ void ln_impl(const float* __restrict__ src,
                                        const float* __restrict__ lnw,
                                        const float* __restrict__ lnb,
                                        float* __restrict__ o1,
                                        float* __restrict__ o2,
                                        float* __restrict__ o3,
                                        float* red){
  int tid = threadIdx.x, lane = tid & 63, wv = tid >> 6;
  float s = 0.f, ss = 0.f;
  for(int i = tid; i < NNODE; i += 256){ float v = src[i]; s += v; ss += v*v; }
  #pragma unroll
  for(int off=1; off<64; off<<=1){ s += __shfl_xor(s, off); ss += __shfl_xor(ss, off); }
  if(lane == 0){ red[wv] = s; red[4+wv] = ss; }
  __syncthreads();
  s  = red[0]+red[1]+red[2]+red[3];
  ss = red[4]+red[5]+red[6]+red[7];
  float mu  = s * (1.0f/NNODE);
  float var = ss * (1.0f/NNODE) - mu*mu;
  float inv = 1.0f / sqrtf(var + 1e-5f);
  for(int i = tid; i < NNODE; i += 256){
    float v = (src[i]-mu)*inv*lnw[i] + lnb[i];
    o1[i] = v; o2[i] = v; o3[i] = v;
  }
  __syncthreads();
}

// ---------- GEMM tile (r7-verified body): C[M,256] = A @ Bt^T, 128x128, 4 waves ----------
template<int AF32>
__device__ __forceinline__ void gemm_tile(const MegaParams& p, int rl, char* smraw,
                                          const void* Av, const unsigned short* Bt,
                                          unsigned short* C, const float* attS,
                                          const float* attD, int K){
  const unsigned short* A = (const unsigned short*)Av;
  const float*         Af = (const float*)Av;
  unsigned short (*As)[LPITCH] = (unsigned short(*)[LPITCH])smraw;
  unsigned short (*Bs)[LPITCH] = (unsigned short(*)[LPITCH])(smraw + 128*LPITCH*2);
  int tid = threadIdx.x;
  int lane = tid & 63, wv = tid >> 6;
  int wm = (wv & 1)*64, wn = (wv >> 1)*64;
  int n0 = (rl & 1)*128, m0 = (rl >> 1)*128;
  int l15 = lane & 15, lq = lane >> 4;
  f32x4 acc[4][4];
  #pragma unroll
  for(int i=0;i<4;i++)
    #pragma unroll
    for(int j=0;j<4;j++)
      acc[i][j] = (f32x4){0.f,0.f,0.f,0.f};

  int r = tid >> 2, c = (tid & 3)*8;
  float rs1 = 0.f, rs2 = 0.f;
  for(int k0 = 0; k0 < K; k0 += BK){
    if(AF32){
      const float* pa  = Af + (size_t)(m0+r)*K + k0 + c;
      const float* pa2 = Af + (size_t)(m0+r+64)*K + k0 + c;
      float4 u0 = ld4(pa),  u1 = ld4(pa+4);
      float4 v0 = ld4(pa2), v1 = ld4(pa2+4);
      rs1 += (u0.x+u0.y+u0.z+u0.w) + (u1.x+u1.y+u1.z+u1.w);
      rs2 += (v0.x+v0.y+v0.z+v0.w) + (v1.x+v1.y+v1.z+v1.w);
      uint4 w0, w1;
      w0.x = pk2bf(u0.x,u0.y); w0.y = pk2bf(u0.z,u0.w);
      w0.z = pk2bf(u1.x,u1.y); w0.w = pk2bf(u1.z,u1.w);
      w1.x = pk2bf(v0.x,v0.y); w1.y = pk2bf(v0.z,v0.w);
      w1.z = pk2bf(v1.x,v1.y); w1.w = pk2bf(v1.z,v1.w);
      *reinterpret_cast<uint4*>(&As[r][c])    = w0;
      *reinterpret_cast<uint4*>(&As[r+64][c]) = w1;
    } else {
      *reinterpret_cast<uint4*>(&As[r][c])    = *reinterpret_cast<const uint4*>(A  + (size_t)(m0+r)*K + k0 + c);
      *reinterpret_cast<uint4*>(&As[r+64][c]) = *reinterpret_cast<const uint4*>(A  + (size_t)(m0+r+64)*K + k0 + c);
    }
    *reinterpret_cast<uint4*>(&Bs[r][c])    = *reinterpret_cast<const uint4*>(Bt + (size_t)(n0+r)*K + k0 + c);
    *reinterpret_cast<uint4*>(&Bs[r+64][c]) = *reinterpret_cast<const uint4*>(Bt + (size_t)(n0+r+64)*K + k0 + c);
    __syncthreads();
    bf16x8 af[4], bfr[4];
    #pragma unroll
    for(int i=0;i<4;i++){
      af[i]  = *reinterpret_cast<const bf16x8*>(&As[wm + i*16 + l15][lq*8]);
      bfr[i] = *reinterpret_cast<const bf16x8*>(&Bs[wn + i*16 + l15][lq*8]);
    }
    #pragma unroll
    for(int mi=0;mi<4;mi++)
      #pragma unroll
      for(int ni=0;ni<4;ni++)
        acc[mi][ni] = __builtin_amdgcn_mfma_f32_16x16x32_bf16(af[mi], bfr[ni], acc[mi][ni], 0, 0, 0);
    __syncthreads();
  }
  if(AF32 && n0 == 0){                            // x0 row means (each row once)
    float s1 = rs1, s2 = rs2;
    s1 += __shfl_xor(s1,1); s1 += __shfl_xor(s1,2);
    s2 += __shfl_xor(s2,1); s2 += __shfl_xor(s2,2);
    if((tid & 3) == 0){
      p.x0r[m0 + r]      = s1 * (1.0f/FIN);
      p.x0r[m0 + r + 64] = s2 * (1.0f/FIN);
    }
  }
  // C/D layout: col = lane&15, row = (lane>>4)*4 + reg
  #pragma unroll
  for(int mi=0;mi<4;mi++){
    #pragma unroll
    for(int ni=0;ni<4;ni++){
      int cn = n0 + wn + ni*16 + l15;
      #pragma unroll
      for(int rg=0;rg<4;rg++){
        int rm = m0 + wm + mi*16 + lq*4 + rg;
        C[(size_t)rm*HCDIM + cn] = f2bf(acc[mi][ni][rg]);
      }
    }
  }
  int head = (n0 + wn) >> 6;
  float avs[4], avd[4];
  #pragma unroll
  for(int ni=0;ni<4;ni++){
    int cc = ni*16 + l15;
    avs[ni] = attS[head*64 + cc];
    avd[ni] = attD[head*64 + cc];
  }
  #pragma unroll
  for(int mi=0;mi<4;mi++){
    #pragma unroll
    for(int rg=0;rg<4;rg++){
      float ps = 0.f, pd = 0.f;
      #pragma unroll
      for(int ni=0;ni<4;ni++){
        float v = acc[mi][ni][rg];
        ps = fmaf(avs[ni], v, ps);
        pd = fmaf(avd[ni], v, pd);
      }
      #pragma unroll
      for(int off=1; off<16; off<<=1){
        ps += __shfl_xor(ps, off);
        pd += __shfl_xor(pd, off);
      }
      if(l15 == 0){
        int rm = m0 + wm + mi*16 + lq*4 + rg;
        p.a_s[rm*4 + head] = ps;
        p.a_d[rm*4 + head] = pd;
      }
    }
  }
}

// ---------- agg role (r7-verified body): softmax+gather+bias+relu+pool, LN piggyback ----------
template<int STORE>
__device__ __forceinline__ void agg_role(const MegaParams& p, int bx, char* smraw,
                                         const unsigned short* hpre, const float* bias,
                                         const float* pw, const float* pb,
                                         unsigned short* hout, float* xraw,
                                         const float* lnsrc, int which){
  float4 (*ew)[CAP]    = (float4(*)[CAP])smraw;               // 4096 B
  int    (*cols)[CAP+1]= (int(*)[CAP+1])(smraw + 4096);       // 1040 B
  float*  lred         = (float*)(smraw + 5152);              // 32 B
  int tid = threadIdx.x;
  if(bx < 16){
    int b = bx;
    ln_impl(lnsrc + b*NNODE, p.lnw, p.lnb,
            p.out + 16 + which*(NB*NNODE) + b*NNODE,
            p.out + 16 + 3*(NB*NNODE) + b*(3*NNODE) + which*NNODE,
            p.tbuf + b*FCIN + 3*NNODE + which*NNODE, lred);
    return;
  }
  int lane = tid & 63, wv = tid >> 6;
  int blk  = bx - 16;
  int xcd  = blk & 7;
  int slot = blk >> 3;
  int half = slot / 500;
  int g    = xcd + 8*half;
  int n    = g*NNODE + (slot - half*500)*4 + wv;
  int f0 = lane*4;
  int hl = lane >> 4;
  float4 ad   = ld4(p.a_d + n*4);
  float4 asn  = ld4(p.a_s + n*4);
  float4 eself = exp4u(leaky4(add4(asn, ad)));
  int deg = min(p.cnt[n], CAP);
  int base = n << 6;
  if(lane < deg){
    int s = p.col[base + lane];
    cols[wv][lane] = s;
    ew[wv][lane] = exp4u(leaky4(add4(ld4(p.a_s + s*4), ad)));
  } else {
    cols[wv][lane] = n;
  }
  if(lane == 0) cols[wv][CAP] = n;
  float es = selh(eself, hl);
  float dsum = es;
  float4 hv = ldbf4(hpre + (size_t)n*HCDIM + f0);
  float4 acc = make_float4(es*hv.x, es*hv.y, es*hv.z, es*hv.w);
  const float* ewf = (const float*)&ew[wv][0];
  const int*   cwf = &cols[wv][0];
  float4 h2 = ldbf4(hpre + (size_t)cwf[0]*HCDIM + f0);
  for(int e = 0; e < deg; e++){
    int sn = cwf[e+1];
    float4 hn = ldbf4(hpre + (size_t)sn*HCDIM + f0);
    float w = ewf[e*4 + hl];
    dsum += w;
    acc.x = fmaf(w, h2.x, acc.x); acc.y = fmaf(w, h2.y, acc.y);
    acc.z = fmaf(w, h2.z, acc.z); acc.w = fmaf(w, h2.w, acc.w);
    h2 = hn;
  }
  float invh = 1.0f / (dsum + 1e-16f);
  float4 b4 = ld4(bias + f0);
  acc = make_float4(fmaxf(fmaf(acc.x,invh,b4.x),0.f), fmaxf(fmaf(acc.y,invh,b4.y),0.f),
                    fmaxf(fmaf(acc.z,invh,b4.z),0.f), fmaxf(fmaf(acc.w,invh,b4.w),0.f));
  if(STORE){
    ushort4 hb = make_ushort4(f2bf(acc.x), f2bf(acc.y), f2bf(acc.z), f2bf(acc.w));
    *reinterpret_cast<ushort4*>(hout + (size_t)n*HCDIM + f0) = hb;
  }
  float part = dot4(acc, ld4(pw + f0));
  #pragma unroll
  for(int off=1; off<64; off<<=1) part += __shfl_xor(part, off);
  if(lane == 0) xraw[n] = part + pb[0];
}

// ---------- barrier-counter init ----------
__global__ void k_init(unsigned int* bar){ if(threadIdx.x == 0) *bar = 0u; }

// ---------- THE persistent mega-kernel: 9 phases, 8 grid barriers ----------
__global__ __launch_bounds__(256, 2) void k_mega(MegaParams p){
  __shared__ __align__(16) char smraw[20608];
  const int tid = threadIdx.x;
  const int bid = blockIdx.x;
  const int lane = tid & 63, wvi = tid >> 6;

  // ---- P0: cnt zero | W transposes | demo fill (all independent)
  for(int role = bid; role < ZB + TRB2 + DEMOB; role += NBLK){
    if(role < ZB){
      int i = role*256 + tid;
      if(i < NTOT) p.cnt[i] = 0;
    } else if(role < ZB + TRB2){
      float (*tile)[65] = (float(*)[65])smraw;
      int tb = role - ZB;
      if(tb < 8){                                 // W1: 128x256 -> W1t 256x128
        int tk = tb >> 2, tn = tb & 3;
        int k0 = tk*64, n0 = tn*64;
        #pragma unroll
        for(int q=0;q<16;q++){
          int row = q*4 + wvi;
          tile[row][lane] = p.W1[(size_t)(k0+row)*HCDIM + n0 + lane];
        }
        __syncthreads();
        #pragma unroll
        for(int q=0;q<16;q++){
          int row = q*4 + wvi;
          p.W1t[(size_t)(n0+row)*FIN + k0 + lane] = f2bf(tile[lane][row]);
        }
        __syncthreads();
      } else {                                    // W2: 256x256 -> W2t 256x256
        int t2 = tb - 8;
        int tk = t2 >> 2, tn = t2 & 3;
        int k0 = tk*64, n0 = tn*64;
        #pragma unroll
        for(int q=0;q<16;q++){
          int row = q*4 + wvi;
          tile[row][lane] = p.W2[(size_t)(k0+row)*HCDIM + n0 + lane];
        }
        __syncthreads();
        #pragma unroll
        for(int q=0;q<16;q++){
          int row = q*4 + wvi;
          p.W2t[(size_t)(n0+row)*HCDIM + k0 + lane] = f2bf(tile[lane][row]);
        }
        __syncthreads();
      }
    } else {
      int i = (role - ZB - TRB2)*256 + tid;
      int b = i / (3*NNODE);
      int j = i - b*(3*NNODE);
      float v;
      if(j < NNODE)          v = p.sexemb[p.sex[b]*NNODE + j];
      else if(j < 2*NNODE)   v = p.mutemb[p.mut[b]*NNODE + (j - NNODE)];
      else                   v = p.age[b]*p.agew[j - 2*NNODE] + p.ageb[j - 2*NNODE];
      p.tbuf[b*FCIN + j] = v;
    }
  }
  gridbar(p.bar);

  // ---- P1: adjacency build (needs cnt=0) | gemm1 + x0 (needs W1t)
  {
    int R1 = p.eb + 500;
    for(int role = bid; role < R1; role += NBLK){
      if(role < p.eb){
        int i = role*256 + tid;
        if(i < p.E0){
          int d = p.edst[i];
          int slot = atomicAdd(&p.cnt[d], 1);
          if(slot < CAP) p.col[(d<<6) + slot] = p.esrc[i];
        }
      } else {
        gemm_tile<1>(p, role - p.eb, smraw, p.x, p.W1t, p.hA, p.attS1, p.attD1, FIN);
      }
    }
  }
  gridbar(p.bar);

  // ---- P2: agg1 + ln(x0) piggyback
  for(int role = bid; role < 16 + NTOT/4; role += NBLK)
    agg_role<1>(p, role, smraw, p.hA, p.b1, p.pw1, p.pb1, p.hB, p.x1r, p.x0r, 0);
  gridbar(p.bar);

  // ---- P3: gemm2
  for(int role = bid; role < 500; role += NBLK)
    gemm_tile<0>(p, role, smraw, p.hB, p.W2t, p.hA, p.attS2, p.attD2, HCDIM);
  gridbar(p.bar);

  // ---- P4: agg2 + ln(x1) piggyback
  for(int role = bid; role < 16 + NTOT/4; role += NBLK)
    agg_role<0>(p, role, smraw, p.hA, p.b2, p.pw2, p.pb2, p.hB, p.x2r, p.x1r, 1);
  gridbar(p.bar);

  // ---- P5: ln(x2)
  for(int role = bid; role < 16; role += NBLK){
    float* red = (float*)smraw;
    ln_impl(p.x2r + role*NNODE, p.lnw, p.lnb,
            p.out + 16 + 2*(NB*NNODE) + role*NNODE,
            p.out + 16 + 3*(NB*NNODE) + role*(3*NNODE) + 2*NNODE,
            p.tbuf + role*FCIN + 3*NNODE + 2*NNODE, red);
  }
  gridbar(p.bar);

  // ---- P6: fc1 split-K (column-per-thread, 16 scalar accumulators)
  for(int role = bid; role < 2*NCH; role += NBLK){
    float (*ts)[KCC] = (float(*)[KCC])smraw;
    int chunk = role >> 1;
    int halfc = role & 1;
    int k0 = chunk * KCC;
    for(int i = tid; i < NB*KCC; i += 256){
      int b = i / KCC, kk = i - b*KCC;
      ts[b][kk] = p.tbuf[b*FCIN + k0 + kk];
    }
    __syncthreads();
    int j = halfc*256 + tid;
    float acc[NB];
    #pragma unroll
    for(int b=0;b<NB;b++) acc[b] = 0.f;
    const float* wp = p.fw1 + (size_t)k0*FC1DIM + j;
    #pragma unroll 8
    for(int kk = 0; kk < KCC; kk++){
      float w = wp[(size_t)kk*FC1DIM];
      #pragma unroll
      for(int b=0;b<NB;b++) acc[b] = fmaf(ts[b][kk], w, acc[b]);
    }
    float* po = p.part + (size_t)chunk*(NB*FC1DIM) + j;
    #pragma unroll
    for(int b=0;b<NB;b++) po[b*FC1DIM] = acc[b];
    __syncthreads();
  }
  gridbar(p.bar);

  // ---- P7: fc1 partial reduce (wide, coalesced)
  for(int role = bid; role < (NB*FC1DIM)/64; role += NBLK){
    float (*red)[64] = (float(*)[64])smraw;
    int e = role*64 + (tid & 63);
    int g = tid >> 6;
    int c0 = (g < 2) ? g*63 : 126 + (g-2)*62;
    int cn = (g < 2) ? 63 : 62;
    float s = 0.f;
    for(int c = c0; c < c0 + cn; c++) s += p.part[(size_t)c*(NB*FC1DIM) + e];
    if(g) red[g-1][tid & 63] = s;
    __syncthreads();
    if(g == 0){
      s += red[0][tid & 63] + red[1][tid & 63] + red[2][tid & 63];
      s += p.fb1[e & (FC1DIM-1)];
      p.t1[e] = fmaxf(s, 0.f);
    }
    __syncthreads();
  }
  gridbar(p.bar);

  // ---- P8: fc2 + relu + fc3 (16 roles)
  for(int role = bid; role < NB; role += NBLK){
    float* red2 = (float*)smraw;
    int b = role;
    float s = 0.f;
    if(tid < FC2DIM){
      int j = tid;
      const float* tr = p.t1 + b*FC1DIM;
      s = p.fb2[j];
      for(int k=0;k<FC1DIM;k++) s = fmaf(tr[k], p.fw2[k*FC2DIM+j], s);
      s = fmaxf(s, 0.f) * p.fw3[j];
      #pragma unroll
      for(int off=1; off<64; off<<=1) s += __shfl_xor(s, off);
      if((tid & 63) == 0) red2[tid >> 6] = s;
    }
    __syncthreads();
    if(tid == 0) p.out[b] = red2[0] + red2[1] + p.fb3[0];
    __syncthreads();
  }
}

extern "C" void kernel_launch(void* const* d_in, const int* in_sizes, int n_in,
                              void* d_out, int out_size, void* d_ws, size_t ws_size,
                              hipStream_t stream) {
  MegaParams p;
  p.x      = (const float*)d_in[0];
  p.W1     = (const float*)d_in[1];
  p.attS1  = (const float*)d_in[2];
  p.attD1  = (const float*)d_in[3];
  p.b1     = (const float*)d_in[4];
  p.W2     = (const float*)d_in[5];
  p.attS2  = (const float*)d_in[6];
  p.attD2  = (const float*)d_in[7];
  p.b2     = (const float*)d_in[8];
  p.pw1    = (const float*)d_in[9];
  p.pb1    = (const float*)d_in[10];
  p.pw2    = (const float*)d_in[11];
  p.pb2    = (const float*)d_in[12];
  p.lnw    = (const float*)d_in[13];
  p.lnb    = (const float*)d_in[14];
  p.sexemb = (const float*)d_in[15];
  p.mutemb = (const float*)d_in[16];
  p.agew   = (const float*)d_in[17];
  p.ageb   = (const float*)d_in[18];
  p.fw1    = (const float*)d_in[19];
  p.fb1    = (const float*)d_in[20];
  p.fw2    = (const float*)d_in[21];
  p.fb2    = (const float*)d_in[22];
  p.fw3    = (const float*)d_in[23];
  p.fb3    = (const float*)d_in[24];
  p.age    = (const float*)d_in[25];
  const int* eidx = (const int*)d_in[26];
  p.sex    = (const int*)d_in[27];
  p.mut    = (const int*)d_in[28];
  p.E0   = in_sizes[26] / 2;
  p.esrc = eidx;
  p.edst = eidx + p.E0;
  p.eb   = (p.E0 + 255)/256;
  p.out  = (float*)d_out;

  // workspace layout (floats first, then bf16/int, barrier counter last)
  float* w = (float*)d_ws;
  p.a_s  = w;                                  // NTOT*NH
  p.a_d  = p.a_s + NTOT*NH;
  p.x0r  = p.a_d + NTOT*NH;                    // NTOT (x0r/x1r/x2r contiguous)
  p.x1r  = p.x0r + NTOT;
  p.x2r  = p.x1r + NTOT;
  p.tbuf = p.x2r + NTOT;                       // NB*FCIN
  p.part = p.tbuf + NB*FCIN;                   // NCH*NB*FC1DIM
  p.t1   = p.part + (size_t)256*NB*FC1DIM;     // NB*FC1DIM
  p.hA   = (unsigned short*)(p.t1 + NB*FC1DIM);       // NTOT*HCDIM bf16
  p.hB   = p.hA + (size_t)NTOT*HCDIM;                 // NTOT*HCDIM bf16
  p.W1t  = p.hB + (size_t)NTOT*HCDIM;                 // HCDIM*FIN bf16
  p.W2t  = p.W1t + HCDIM*FIN;                         // HCDIM*HCDIM bf16
  p.cnt  = (int*)(p.W2t + HCDIM*HCDIM);               // NTOT
  p.col  = p.cnt + NTOT;                              // NTOT*CAP
  p.bar  = (unsigned int*)(p.col + (size_t)NTOT*CAP); // 1
  (void)ws_size; (void)n_in; (void)out_size;

  k_init<<<1, 64, 0, stream>>>(p.bar);
  k_mega<<<NBLK, 256, 0, stream>>>(p);
}

// Round 9
// 285.782 us; speedup vs baseline: 3.5439x; 3.5439x over previous
//
#include <hip/hip_runtime.h>
#include <math.h>

#define NTOT   32000      // total nodes
#define NNODE  2000       // nodes per graph
#define NB     16         // batch (graphs)
#define FIN    128        // input features
#define HCDIM  256        // heads*channels
#define NH     4          // heads
#define FC1DIM 512
#define FC2DIM 128
#define FCIN   12000      // 6*NNODE
#define NCH    250        // fc1 k-chunks
#define KCC    48         // fc1 k-rows per chunk (250*48 = 12000)
#define CAP    64         // padded adjacency capacity per node
#define BK     32
#define LPITCH 40         // LDS row pitch in bf16
#define ZB     125        // cnt-zero roles (125*256 = 32000)
#define TRB2   24         // tiled-transpose roles
#define DEMOB  375        // demo-fill roles (375*256 = 96000)
#define FC1A   416        // fc1 roles in tailA (chunks 0..207)
#define FC1B   84         // fc1 roles in fc1b (chunks 208..249)

typedef __attribute__((ext_vector_type(8))) short bf16x8;
typedef __attribute__((ext_vector_type(4))) float f32x4;

// ---------- small helpers ----------
__device__ inline float4 ld4(const float* p){ return *reinterpret_cast<const float4*>(p); }
__device__ inline float4 add4(float4 a, float4 b){ return make_float4(a.x+b.x,a.y+b.y,a.z+b.z,a.w+b.w); }
__device__ inline float lrelu(float x){ return x > 0.f ? x : 0.2f*x; }
__device__ inline float4 leaky4(float4 a){ return make_float4(lrelu(a.x),lrelu(a.y),lrelu(a.z),lrelu(a.w)); }
__device__ inline float4 exp4u(float4 a){ return make_float4(__expf(a.x),__expf(a.y),__expf(a.z),__expf(a.w)); }
__device__ inline float dot4(float4 a, float4 b){ return a.x*b.x + a.y*b.y + a.z*b.z + a.w*b.w; }
__device__ inline float selh(float4 v, int h){ return h==0 ? v.x : (h==1 ? v.y : (h==2 ? v.z : v.w)); }

__device__ inline unsigned short f2bf(float f){
  unsigned int u = __float_as_uint(f);
  u += 0x7FFFu + ((u >> 16) & 1u);
  return (unsigned short)(u >> 16);
}
__device__ inline unsigned int pk2bf(float a, float b){
  return (unsigned int)f2bf(a) | ((unsigned int)f2bf(b) << 16);
}
__device__ inline float bf2f(unsigned short h){
  return __uint_as_float(((unsigned int)h) << 16);
}
__device__ inline float4 ldbf4(const unsigned short* p){
  ushort4 v = *reinterpret_cast<const ushort4*>(p);
  return make_float4(bf2f(v.x), bf2f(v.y), bf2f(v.z), bf2f(v.w));
}

// ---------- layernorm over one graph's 2000 values (one 256-thr block) ----------
__device__ __forceinline__ void ln_impl(const float* __restrict__ src,
                                        const float* __restrict__ lnw,
                                        const float* __restrict__ lnb,
                                        float* __restrict__ o1,
                                        float* __restrict__ o2,
                                        float* __restrict__ o3,
                                        float* red){
  int tid = threadIdx.x, lane = tid & 63, wv = tid >> 6;
  float s = 0.f, ss = 0.f;
  for(int i = tid; i < NNODE; i += 256){ float v = src[i]; s += v; ss += v*v; }
  #pragma unroll
  for(int off=1; off<64; off<<=1){ s += __shfl_xor(s, off); ss += __shfl_xor(ss, off); }
  if(lane == 0){ red[wv] = s; red[4+wv] = ss; }
  __syncthreads();
  s  = red[0]+red[1]+red[2]+red[3];
  ss = red[4]+red[5]+red[6]+red[7];
  float mu  = s * (1.0f/NNODE);
  float var = ss * (1.0f/NNODE) - mu*mu;
  float inv = 1.0f / sqrtf(var + 1e-5f);
  for(int i = tid; i < NNODE; i += 256){
    float v = (src[i]-mu)*inv*lnw[i] + lnb[i];
    o1[i] = v; o2[i] = v; o3[i] = v;
  }
}

// ---------- prep: cnt zero | coalesced W transposes | demo fill (one launch) ----------
__global__ __launch_bounds__(256) void k_prep(int* __restrict__ cnt,
                       const float* __restrict__ W1, const float* __restrict__ W2,
                       unsigned short* __restrict__ W1t, unsigned short* __restrict__ W2t,
                       const float* __restrict__ sexemb, const float* __restrict__ mutemb,
                       const float* __restrict__ agew, const float* __restrict__ ageb,
                       const float* __restrict__ age, const int* __restrict__ sex,
                       const int* __restrict__ mut, float* __restrict__ t){
  __shared__ float tile[64][65];
  int blk = blockIdx.x;
  if(blk < ZB){                                   // ---- cnt zero
    cnt[blk*256 + threadIdx.x] = 0;
  } else if(blk < ZB + TRB2){                     // ---- 64x64 tiled transposes
    int tb = blk - ZB;
    int wv = threadIdx.x >> 6, lane = threadIdx.x & 63;
    if(tb < 8){                                   // W1: 128x256 -> W1t 256x128
      int tk = tb >> 2, tn = tb & 3;
      int k0 = tk*64, n0 = tn*64;
      #pragma unroll
      for(int q=0;q<16;q++){
        int row = q*4 + wv;
        tile[row][lane] = W1[(size_t)(k0+row)*HCDIM + n0 + lane];
      }
      __syncthreads();
      #pragma unroll
      for(int q=0;q<16;q++){
        int row = q*4 + wv;
        W1t[(size_t)(n0+row)*FIN + k0 + lane] = f2bf(tile[lane][row]);
      }
    } else {                                      // W2: 256x256 -> W2t 256x256
      int t2 = tb - 8;
      int tk = t2 >> 2, tn = t2 & 3;
      int k0 = tk*64, n0 = tn*64;
      #pragma unroll
      for(int q=0;q<16;q++){
        int row = q*4 + wv;
        tile[row][lane] = W2[(size_t)(k0+row)*HCDIM + n0 + lane];
      }
      __syncthreads();
      #pragma unroll
      for(int q=0;q<16;q++){
        int row = q*4 + wv;
        W2t[(size_t)(n0+row)*HCDIM + k0 + lane] = f2bf(tile[lane][row]);
      }
    }
  } else {                                        // ---- demographic part of t
    int i = (blk - ZB - TRB2)*256 + threadIdx.x;
    int b = i / (3*NNODE);
    int j = i - b*(3*NNODE);
    float v;
    if(j < NNODE)          v = sexemb[sex[b]*NNODE + j];
    else if(j < 2*NNODE)   v = mutemb[mut[b]*NNODE + (j - NNODE)];
    else                   v = age[b]*agew[j - 2*NNODE] + ageb[j - 2*NNODE];
    t[b*FCIN + j] = v;
  }
}

// ---------- GEMM tile (r7/r8-verified body): C[M,256] = A @ Bt^T, 128x128, 4 waves ----------
// rl: rl&1 -> n-tile (0/1), rl>>1 -> m-tile (0..249). AF32: f32 A, bf16-convert in
// staging, + x0 row-means on n0==0 tiles.
template<int AF32>
__device__ __forceinline__ void gemm_tile(int rl, char* smraw,
                                          const void* Av, const unsigned short* Bt,
                                          unsigned short* C, const float* attS,
                                          const float* attD, float* a_s, float* a_d,
                                          float* x0r, int K){
  const unsigned short* A = (const unsigned short*)Av;
  const float*         Af = (const float*)Av;
  unsigned short (*As)[LPITCH] = (unsigned short(*)[LPITCH])smraw;
  unsigned short (*Bs)[LPITCH] = (unsigned short(*)[LPITCH])(smraw + 128*LPITCH*2);
  int tid = threadIdx.x;
  int lane = tid & 63, wv = tid >> 6;
  int wm = (wv & 1)*64, wn = (wv >> 1)*64;
  int n0 = (rl & 1)*128, m0 = (rl >> 1)*128;
  int l15 = lane & 15, lq = lane >> 4;
  f32x4 acc[4][4];
  #pragma unroll
  for(int i=0;i<4;i++)
    #pragma unroll
    for(int j=0;j<4;j++)
      acc[i][j] = (f32x4){0.f,0.f,0.f,0.f};

  int r = tid >> 2, c = (tid & 3)*8;
  float rs1 = 0.f, rs2 = 0.f;
  for(int k0 = 0; k0 < K; k0 += BK){
    if(AF32){
      const float* pa  = Af + (size_t)(m0+r)*K + k0 + c;
      const float* pa2 = Af + (size_t)(m0+r+64)*K + k0 + c;
      float4 u0 = ld4(pa),  u1 = ld4(pa+4);
      float4 v0 = ld4(pa2), v1 = ld4(pa2+4);
      rs1 += (u0.x+u0.y+u0.z+u0.w) + (u1.x+u1.y+u1.z+u1.w);
      rs2 += (v0.x+v0.y+v0.z+v0.w) + (v1.x+v1.y+v1.z+v1.w);
      uint4 w0, w1;
      w0.x = pk2bf(u0.x,u0.y); w0.y = pk2bf(u0.z,u0.w);
      w0.z = pk2bf(u1.x,u1.y); w0.w = pk2bf(u1.z,u1.w);
      w1.x = pk2bf(v0.x,v0.y); w1.y = pk2bf(v0.z,v0.w);
      w1.z = pk2bf(v1.x,v1.y); w1.w = pk2bf(v1.z,v1.w);
      *reinterpret_cast<uint4*>(&As[r][c])    = w0;
      *reinterpret_cast<uint4*>(&As[r+64][c]) = w1;
    } else {
      *reinterpret_cast<uint4*>(&As[r][c])    = *reinterpret_cast<const uint4*>(A  + (size_t)(m0+r)*K + k0 + c);
      *reinterpret_cast<uint4*>(&As[r+64][c]) = *reinterpret_cast<const uint4*>(A  + (size_t)(m0+r+64)*K + k0 + c);
    }
    *reinterpret_cast<uint4*>(&Bs[r][c])    = *reinterpret_cast<const uint4*>(Bt + (size_t)(n0+r)*K + k0 + c);
    *reinterpret_cast<uint4*>(&Bs[r+64][c]) = *reinterpret_cast<const uint4*>(Bt + (size_t)(n0+r+64)*K + k0 + c);
    __syncthreads();
    bf16x8 af[4], bfr[4];
    #pragma unroll
    for(int i=0;i<4;i++){
      af[i]  = *reinterpret_cast<const bf16x8*>(&As[wm + i*16 + l15][lq*8]);
      bfr[i] = *reinterpret_cast<const bf16x8*>(&Bs[wn + i*16 + l15][lq*8]);
    }
    #pragma unroll
    for(int mi=0;mi<4;mi++)
      #pragma unroll
      for(int ni=0;ni<4;ni++)
        acc[mi][ni] = __builtin_amdgcn_mfma_f32_16x16x32_bf16(af[mi], bfr[ni], acc[mi][ni], 0, 0, 0);
    __syncthreads();
  }
  if(AF32 && n0 == 0){                            // x0 row means (each row once)
    float s1 = rs1, s2 = rs2;
    s1 += __shfl_xor(s1,1); s1 += __shfl_xor(s1,2);
    s2 += __shfl_xor(s2,1); s2 += __shfl_xor(s2,2);
    if((tid & 3) == 0){
      x0r[m0 + r]      = s1 * (1.0f/FIN);
      x0r[m0 + r + 64] = s2 * (1.0f/FIN);
    }
  }
  // C/D layout: col = lane&15, row = (lane>>4)*4 + reg
  #pragma unroll
  for(int mi=0;mi<4;mi++){
    #pragma unroll
    for(int ni=0;ni<4;ni++){
      int cn = n0 + wn + ni*16 + l15;
      #pragma unroll
      for(int rg=0;rg<4;rg++){
        int rm = m0 + wm + mi*16 + lq*4 + rg;
        C[(size_t)rm*HCDIM + cn] = f2bf(acc[mi][ni][rg]);
      }
    }
  }
  int head = (n0 + wn) >> 6;
  float avs[4], avd[4];
  #pragma unroll
  for(int ni=0;ni<4;ni++){
    int cc = ni*16 + l15;
    avs[ni] = attS[head*64 + cc];
    avd[ni] = attD[head*64 + cc];
  }
  #pragma unroll
  for(int mi=0;mi<4;mi++){
    #pragma unroll
    for(int rg=0;rg<4;rg++){
      float ps = 0.f, pd = 0.f;
      #pragma unroll
      for(int ni=0;ni<4;ni++){
        float v = acc[mi][ni][rg];
        ps = fmaf(avs[ni], v, ps);
        pd = fmaf(avd[ni], v, pd);
      }
      #pragma unroll
      for(int off=1; off<16; off<<=1){
        ps += __shfl_xor(ps, off);
        pd += __shfl_xor(pd, off);
      }
      if(l15 == 0){
        int rm = m0 + wm + mi*16 + lq*4 + rg;
        a_s[rm*4 + head] = ps;
        a_d[rm*4 + head] = pd;
      }
    }
  }
}

// ---------- launch B: gemm1 (roles 0..499) | adjacency build (roles 500..) ----------
// Independent outputs (hA/a_s/a_d/x0r vs cnt/col); gemm first = long pole scheduled first.
__global__ __launch_bounds__(256) void k_bg1(const float* __restrict__ x,
                                             const unsigned short* __restrict__ W1t,
                                             unsigned short* __restrict__ hA,
                                             const float* __restrict__ attS1,
                                             const float* __restrict__ attD1,
                                             float* __restrict__ a_s,
                                             float* __restrict__ a_d,
                                             float* __restrict__ x0r,
                                             const int* __restrict__ esrc,
                                             const int* __restrict__ edst,
                                             int* __restrict__ cnt,
                                             int* __restrict__ col, int E0){
  __shared__ __align__(16) char smraw[128*LPITCH*4];
  int bid = blockIdx.x;
  if(bid < 500){
    gemm_tile<1>(bid, smraw, x, W1t, hA, attS1, attD1, a_s, a_d, x0r, FIN);
  } else {
    int i = (bid - 500)*256 + threadIdx.x;
    if(i < E0){
      int d = edst[i];
      int slot = atomicAdd(&cnt[d], 1);
      if(slot < CAP) col[(d<<6) + slot] = esrc[i];
    }
  }
}

// ---------- gemm2 wrapper ----------
__global__ __launch_bounds__(256) void k_gemm2(const unsigned short* __restrict__ hB,
                                               const unsigned short* __restrict__ W2t,
                                               unsigned short* __restrict__ hA,
                                               const float* __restrict__ attS2,
                                               const float* __restrict__ attD2,
                                               float* __restrict__ a_s,
                                               float* __restrict__ a_d){
  __shared__ __align__(16) char smraw[128*LPITCH*4];
  gemm_tile<0>(blockIdx.x, smraw, hB, W2t, hA, attS2, attD2, a_s, a_d, (float*)0, HCDIM);
}

// ---------- fused softmax + aggregation + bias + relu + pool-dot (r7 body) ----------
template<int STORE>
__global__ __launch_bounds__(256) void k_agg(const unsigned short* __restrict__ hpre,
                                             const float* __restrict__ a_s,
                                             const float* __restrict__ a_d,
                                             const int* __restrict__ cnt,
                                             const int* __restrict__ col,
                                             const float* __restrict__ bias,
                                             const float* __restrict__ pw,
                                             const float* __restrict__ pb,
                                             unsigned short* __restrict__ hout,
                                             float* __restrict__ xraw,
                                             const float* __restrict__ lnsrc,
                                             const float* __restrict__ lnw,
                                             const float* __restrict__ lnb,
                                             float* __restrict__ out,
                                             float* __restrict__ t,
                                             int which){
  __shared__ float4 ew[4][CAP];
  __shared__ int    cols[4][CAP+1];
  __shared__ float  lred[8];
  int bx = blockIdx.x;
  if(bx < 16){                                    // ---- piggybacked layernorm
    int b = bx;
    ln_impl(lnsrc + b*NNODE, lnw, lnb,
            out + 16 + which*(NB*NNODE) + b*NNODE,
            out + 16 + 3*(NB*NNODE) + b*(3*NNODE) + which*NNODE,
            t + b*FCIN + 3*NNODE + which*NNODE, lred);
    return;
  }
  int tid = threadIdx.x;
  int lane = tid & 63, wv = tid >> 6;
  int blk  = bx - 16;
  int xcd  = blk & 7;
  int slot = blk >> 3;
  int half = slot / 500;
  int g    = xcd + 8*half;
  int n    = g*NNODE + (slot - half*500)*4 + wv;
  int f0 = lane*4;
  int hl = lane >> 4;
  float4 ad   = ld4(a_d + n*4);
  float4 asn  = ld4(a_s + n*4);
  float4 eself = exp4u(leaky4(add4(asn, ad)));
  int deg = min(cnt[n], CAP);
  int base = n << 6;
  if(lane < deg){
    int s = col[base + lane];
    cols[wv][lane] = s;
    ew[wv][lane] = exp4u(leaky4(add4(ld4(a_s + s*4), ad)));
  } else {
    cols[wv][lane] = n;
  }
  if(lane == 0) cols[wv][CAP] = n;
  float es = selh(eself, hl);
  float dsum = es;
  float4 hv = ldbf4(hpre + (size_t)n*HCDIM + f0);
  float4 acc = make_float4(es*hv.x, es*hv.y, es*hv.z, es*hv.w);
  const float* ewf = (const float*)&ew[wv][0];
  const int*   cwf = &cols[wv][0];
  float4 h2 = ldbf4(hpre + (size_t)cwf[0]*HCDIM + f0);
  for(int e = 0; e < deg; e++){
    int sn = cwf[e+1];
    float4 hn = ldbf4(hpre + (size_t)sn*HCDIM + f0);
    float w = ewf[e*4 + hl];
    dsum += w;
    acc.x = fmaf(w, h2.x, acc.x); acc.y = fmaf(w, h2.y, acc.y);
    acc.z = fmaf(w, h2.z, acc.z); acc.w = fmaf(w, h2.w, acc.w);
    h2 = hn;
  }
  float invh = 1.0f / (dsum + 1e-16f);
  float4 b4 = ld4(bias + f0);
  acc = make_float4(fmaxf(fmaf(acc.x,invh,b4.x),0.f), fmaxf(fmaf(acc.y,invh,b4.y),0.f),
                    fmaxf(fmaf(acc.z,invh,b4.z),0.f), fmaxf(fmaf(acc.w,invh,b4.w),0.f));
  if(STORE){
    ushort4 hb = make_ushort4(f2bf(acc.x), f2bf(acc.y), f2bf(acc.z), f2bf(acc.w));
    *reinterpret_cast<ushort4*>(hout + (size_t)n*HCDIM + f0) = hb;
  }
  float part = dot4(acc, ld4(pw + f0));
  #pragma unroll
  for(int off=1; off<64; off<<=1) part += __shfl_xor(part, off);
  if(lane == 0) xraw[n] = part + pb[0];
}

// ---------- fc1 role body (column-per-thread, 16 scalar accumulators) ----------
__device__ __forceinline__ void fc1_role(int role, float* tsraw,
                                         const float* __restrict__ t,
                                         const float* __restrict__ fw1,
                                         float* __restrict__ partial){
  float (*ts)[KCC] = (float(*)[KCC])tsraw;
  int chunk = role >> 1;
  int halfc = role & 1;
  int tid = threadIdx.x;
  int k0 = chunk * KCC;
  for(int i = tid; i < NB*KCC; i += 256){
    int b = i / KCC, kk = i - b*KCC;
    ts[b][kk] = t[b*FCIN + k0 + kk];
  }
  __syncthreads();
  int j = halfc*256 + tid;
  float acc[NB];
  #pragma unroll
  for(int b=0;b<NB;b++) acc[b] = 0.f;
  const float* wp = fw1 + (size_t)k0*FC1DIM + j;
  #pragma unroll 8
  for(int kk = 0; kk < KCC; kk++){
    float w = wp[(size_t)kk*FC1DIM];
    #pragma unroll
    for(int b=0;b<NB;b++) acc[b] = fmaf(ts[b][kk], w, acc[b]);
  }
  float* po = partial + (size_t)chunk*(NB*FC1DIM) + j;
  #pragma unroll
  for(int b=0;b<NB;b++) po[b*FC1DIM] = acc[b];
}

// ---------- tail A: ln(x2) (roles 0..15) | fc1 chunks 0..207 (roles 16..431) ----------
// fc1 chunks 0..207 read t[k<9984] (demo + ln0 + ln1 regions: all ready before this
// launch); ln(x2) writes t's x2 region consumed only by k_fc1b (next launch).
__global__ __launch_bounds__(256) void k_tailA(const float* __restrict__ x2r,
                                               const float* __restrict__ lnw,
                                               const float* __restrict__ lnb,
                                               float* __restrict__ out,
                                               float* __restrict__ t,
                                               const float* __restrict__ fw1,
                                               float* __restrict__ partial){
  __shared__ __align__(16) float tsraw[NB*KCC];
  __shared__ float red[8];
  int bx = blockIdx.x;
  if(bx < 16){
    int b = bx;
    ln_impl(x2r + b*NNODE, lnw, lnb,
            out + 16 + 2*(NB*NNODE) + b*NNODE,
            out + 16 + 3*(NB*NNODE) + b*(3*NNODE) + 2*NNODE,
            t + b*FCIN + 3*NNODE + 2*NNODE, red);
    return;
  }
  fc1_role(bx - 16, tsraw, t, fw1, partial);
}

// ---------- tail B: fc1 chunks 208..249 (need ln(x2) from tailA) ----------
__global__ __launch_bounds__(256) void k_fc1b(const float* __restrict__ t,
                                              const float* __restrict__ fw1,
                                              float* __restrict__ partial){
  __shared__ __align__(16) float tsraw[NB*KCC];
  fc1_role(FC1A + blockIdx.x, tsraw, t, fw1, partial);
}

// ---------- fc1 partial reduce: 128 blocks, 4 wave-groups over 250 chunks ----------
__global__ __launch_bounds__(256) void k_fc1r(const float* __restrict__ partial,
                                              const float* __restrict__ fb1,
                                              float* __restrict__ t1){
  __shared__ float red[3][64];
  int tid = threadIdx.x;
  int e = blockIdx.x*64 + (tid & 63);
  int g = tid >> 6;
  int c0 = (g < 2) ? g*63 : 126 + (g-2)*62;
  int cn = (g < 2) ? 63 : 62;
  float s = 0.f;
  for(int c = c0; c < c0 + cn; c++) s += partial[(size_t)c*(NB*FC1DIM) + e];
  if(g) red[g-1][tid & 63] = s;
  __syncthreads();
  if(g == 0){
    s += red[0][tid & 63] + red[1][tid & 63] + red[2][tid & 63];
    s += fb1[e & (FC1DIM-1)];
    t1[e] = fmaxf(s, 0.f);
  }
}

// ---------- fc2 + relu + fc3 fused: one block per batch ----------
__global__ __launch_bounds__(128) void k_head2(const float* __restrict__ t1,
                                               const float* __restrict__ fw2,
                                               const float* __restrict__ fb2,
                                               const float* __restrict__ fw3,
                                               const float* __restrict__ fb3,
                                               float* __restrict__ pred){
  __shared__ float red[2];
  int b = blockIdx.x, j = threadIdx.x;
  const float* tr = t1 + b*FC1DIM;
  float s = fb2[j];
  for(int k=0;k<FC1DIM;k++) s = fmaf(tr[k], fw2[k*FC2DIM+j], s);
  s = fmaxf(s, 0.f) * fw3[j];
  #pragma unroll
  for(int off=1; off<64; off<<=1) s += __shfl_xor(s, off);
  int lane = j & 63, wv = j >> 6;
  if(lane == 0) red[wv] = s;
  __syncthreads();
  if(j == 0) pred[b] = red[0] + red[1] + fb3[0];
}

extern "C" void kernel_launch(void* const* d_in, const int* in_sizes, int n_in,
                              void* d_out, int out_size, void* d_ws, size_t ws_size,
                              hipStream_t stream) {
  const float* x       = (const float*)d_in[0];
  const float* W1      = (const float*)d_in[1];
  const float* attS1   = (const float*)d_in[2];
  const float* attD1   = (const float*)d_in[3];
  const float* b1      = (const float*)d_in[4];
  const float* W2      = (const float*)d_in[5];
  const float* attS2   = (const float*)d_in[6];
  const float* attD2   = (const float*)d_in[7];
  const float* b2      = (const float*)d_in[8];
  const float* pw1     = (const float*)d_in[9];
  const float* pb1     = (const float*)d_in[10];
  const float* pw2     = (const float*)d_in[11];
  const float* pb2     = (const float*)d_in[12];
  const float* lnw     = (const float*)d_in[13];
  const float* lnb     = (const float*)d_in[14];
  const float* sexemb  = (const float*)d_in[15];
  const float* mutemb  = (const float*)d_in[16];
  const float* agew    = (const float*)d_in[17];
  const float* ageb    = (const float*)d_in[18];
  const float* fw1     = (const float*)d_in[19];
  const float* fb1     = (const float*)d_in[20];
  const float* fw2     = (const float*)d_in[21];
  const float* fb2     = (const float*)d_in[22];
  const float* fw3     = (const float*)d_in[23];
  const float* fb3     = (const float*)d_in[24];
  const float* age     = (const float*)d_in[25];
  const int*   eidx    = (const int*)d_in[26];
  const int*   sex     = (const int*)d_in[27];
  const int*   mut     = (const int*)d_in[28];
  const int E0 = in_sizes[26] / 2;
  const int* esrc = eidx;
  const int* edst = eidx + E0;

  float* out = (float*)d_out;

  // workspace layout (floats first, then bf16/int)
  float* w = (float*)d_ws;
  float* a_s  = w;                        // NTOT*NH
  float* a_d  = a_s + NTOT*NH;
  float* x0r  = a_d + NTOT*NH;            // NTOT (x0r/x1r/x2r contiguous)
  float* x1r  = x0r + NTOT;
  float* x2r  = x1r + NTOT;
  float* tbuf = x2r + NTOT;               // NB*FCIN
  float* part = tbuf + NB*FCIN;           // NCH*NB*FC1DIM (250 chunks)
  float* t1   = part + (size_t)256*NB*FC1DIM;  // NB*FC1DIM
  unsigned short* hA  = (unsigned short*)(t1 + NB*FC1DIM);  // NTOT*HCDIM bf16
  unsigned short* hB  = hA  + (size_t)NTOT*HCDIM;           // NTOT*HCDIM bf16
  unsigned short* W1t = hB  + (size_t)NTOT*HCDIM;           // HCDIM*FIN bf16
  unsigned short* W2t = W1t + HCDIM*FIN;                    // HCDIM*HCDIM bf16
  int* cnt    = (int*)(W2t + HCDIM*HCDIM);   // NTOT
  int* col    = cnt + NTOT;                  // NTOT*CAP
  (void)ws_size; (void)n_in; (void)out_size;

  const int eb = (E0 + 255)/256;

  // A: prep (cnt zero | W transposes | demo)
  k_prep<<<ZB + TRB2 + DEMOB, 256, 0, stream>>>(cnt, W1, W2, W1t, W2t,
                                                sexemb, mutemb, agew, ageb,
                                                age, sex, mut, tbuf);

  // B: gemm1 (+x0 mean, attn epilogue) || adjacency build
  k_bg1<<<500 + eb, 256, 0, stream>>>(x, W1t, hA, attS1, attD1, a_s, a_d, x0r,
                                      esrc, edst, cnt, col, E0);

  // C: agg1 + ln(x0) piggyback
  k_agg<1><<<16 + NTOT/4, 256, 0, stream>>>(hA, a_s, a_d, cnt, col, b1, pw1, pb1, hB, x1r,
                                            x0r, lnw, lnb, out, tbuf, 0);

  // D: gemm2
  k_gemm2<<<500, 256, 0, stream>>>(hB, W2t, hA, attS2, attD2, a_s, a_d);

  // E: agg2 + ln(x1) piggyback
  k_agg<0><<<16 + NTOT/4, 256, 0, stream>>>(hA, a_s, a_d, cnt, col, b2, pw2, pb2, hB, x2r,
                                            x1r, lnw, lnb, out, tbuf, 1);

  // F: ln(x2) || fc1 chunks 0..207
  k_tailA<<<16 + FC1A, 256, 0, stream>>>(x2r, lnw, lnb, out, tbuf, fw1, part);

  // G: fc1 chunks 208..249 (x2 region of t now ready)
  k_fc1b<<<FC1B, 256, 0, stream>>>(tbuf, fw1, part);

  // H: fc1 partial reduce -> t1
  k_fc1r<<<(NB*FC1DIM)/64, 256, 0, stream>>>(part, fb1, t1);

  // I: fc2 + relu + fc3
  k_head2<<<NB, 128, 0, stream>>>(t1, fw2, fb2, fw3, fb3, out);
}

// Round 10
// 282.499 us; speedup vs baseline: 3.5851x; 1.0116x over previous
//
#include <hip/hip_runtime.h>
#include <math.h>

#define NTOT   32000      // total nodes
#define NNODE  2000       // nodes per graph
#define NB     16         // batch (graphs)
#define FIN    128        // input features
#define HCDIM  256        // heads*channels
#define NH     4          // heads
#define FC1DIM 512
#define FC2DIM 128
#define FCIN   12000      // 6*NNODE
#define NCH    250        // fc1 k-chunks
#define KCC    48         // fc1 k-rows per chunk (250*48 = 12000)
#define CAP    64         // padded adjacency capacity per node (deg ~ Poisson(12))
#define BK     32
#define LPITCH 40         // LDS row pitch in bf16 (80B: 16B-aligned, bank-spread)
#define TRB    384        // (HCDIM*FIN + HCDIM*HCDIM)/256 transpose blocks
#define DEMOB  375        // NB*3*NNODE/256 demo blocks

typedef __attribute__((ext_vector_type(8))) short bf16x8;
typedef __attribute__((ext_vector_type(4))) float f32x4;

// ---------- small helpers ----------
__device__ inline float4 ld4(const float* p){ return *reinterpret_cast<const float4*>(p); }
__device__ inline void st4(float* p, float4 v){ *reinterpret_cast<float4*>(p) = v; }
__device__ inline float4 add4(float4 a, float4 b){ return make_float4(a.x+b.x,a.y+b.y,a.z+b.z,a.w+b.w); }
__device__ inline float lrelu(float x){ return x > 0.f ? x : 0.2f*x; }
__device__ inline float4 leaky4(float4 a){ return make_float4(lrelu(a.x),lrelu(a.y),lrelu(a.z),lrelu(a.w)); }
__device__ inline float4 exp4u(float4 a){ return make_float4(__expf(a.x),__expf(a.y),__expf(a.z),__expf(a.w)); }
__device__ inline float dot4(float4 a, float4 b){ return a.x*b.x + a.y*b.y + a.z*b.z + a.w*b.w; }
__device__ inline float selh(float4 v, int h){ return h==0 ? v.x : (h==1 ? v.y : (h==2 ? v.z : v.w)); }

__device__ inline unsigned short f2bf(float f){
  unsigned int u = __float_as_uint(f);
  u += 0x7FFFu + ((u >> 16) & 1u);
  return (unsigned short)(u >> 16);
}
__device__ inline unsigned int pk2bf(float a, float b){
  return (unsigned int)f2bf(a) | ((unsigned int)f2bf(b) << 16);
}
__device__ inline float bf2f(unsigned short h){
  return __uint_as_float(((unsigned int)h) << 16);
}
__device__ inline float4 ldbf4(const unsigned short* p){
  ushort4 v = *reinterpret_cast<const ushort4*>(p);
  return make_float4(bf2f(v.x), bf2f(v.y), bf2f(v.z), bf2f(v.w));
}

// ---------- zero the adjacency counters ----------
__global__ __launch_bounds__(256) void k_zero(int* __restrict__ cnt){
  int i = blockIdx.x*256 + threadIdx.x;
  if(i < NTOT) cnt[i] = 0;
}

// ---------- layernorm over one graph's 2000 values (one 256-thr block) ----------
__device__ __forceinline__ void ln_impl(const float* __restrict__ src,
                                        const float* __restrict__ lnw,
                                        const float* __restrict__ lnb,
                                        float* __restrict__ o1,
                                        float* __restrict__ o2,
                                        float* __restrict__ o3,
                                        float* red){
  int tid = threadIdx.x, lane = tid & 63, wv = tid >> 6;
  float s = 0.f, ss = 0.f;
  for(int i = tid; i < NNODE; i += 256){ float v = src[i]; s += v; ss += v*v; }
  #pragma unroll
  for(int off=1; off<64; off<<=1){ s += __shfl_xor(s, off); ss += __shfl_xor(ss, off); }
  if(lane == 0){ red[wv] = s; red[4+wv] = ss; }
  __syncthreads();
  s  = red[0]+red[1]+red[2]+red[3];
  ss = red[4]+red[5]+red[6]+red[7];
  float mu  = s * (1.0f/NNODE);
  float var = ss * (1.0f/NNODE) - mu*mu;
  float inv = 1.0f / sqrtf(var + 1e-5f);
  for(int i = tid; i < NNODE; i += 256){
    float v = (src[i]-mu)*inv*lnw[i] + lnb[i];
    o1[i] = v; o2[i] = v; o3[i] = v;
  }
}

// ---------- misc: adjacency build | W transposes | demo fill | x row-means ----------
// (r2-measured body, verbatim)
__global__ void k_misc(const int* __restrict__ src, const int* __restrict__ dst,
                       int* __restrict__ cnt, int* __restrict__ col, int e0, int eb,
                       const float* __restrict__ W1, const float* __restrict__ W2,
                       unsigned short* __restrict__ W1t, unsigned short* __restrict__ W2t,
                       const float* __restrict__ sexemb, const float* __restrict__ mutemb,
                       const float* __restrict__ agew, const float* __restrict__ ageb,
                       const float* __restrict__ age, const int* __restrict__ sex,
                       const int* __restrict__ mut, float* __restrict__ t,
                       const float* __restrict__ x, float* __restrict__ x0r){
  int blk = blockIdx.x;
  if(blk < eb){                                   // ---- adjacency build
    int i = blk*256 + threadIdx.x;
    if(i < e0){
      int d = dst[i];
      int slot = atomicAdd(&cnt[d], 1);
      if(slot < CAP) col[(d<<6) + slot] = src[i];
    }
  } else if(blk < eb + TRB){                      // ---- weight transposes + bf16
    int idx = (blk - eb)*256 + threadIdx.x;
    if(idx < HCDIM*FIN){
      int n = idx / FIN, k = idx - n*FIN;
      W1t[idx] = f2bf(W1[(size_t)k*HCDIM + n]);
    } else {
      int j = idx - HCDIM*FIN;
      int n = j / HCDIM, k = j - n*HCDIM;
      W2t[j] = f2bf(W2[(size_t)k*HCDIM + n]);
    }
  } else if(blk < eb + TRB + DEMOB){              // ---- demographic part of t
    int i = (blk - eb - TRB)*256 + threadIdx.x;
    int b = i / (3*NNODE);
    int j = i - b*(3*NNODE);
    float v;
    if(j < NNODE)          v = sexemb[sex[b]*NNODE + j];
    else if(j < 2*NNODE)   v = mutemb[mut[b]*NNODE + (j - NNODE)];
    else                   v = age[b]*agew[j - 2*NNODE] + ageb[j - 2*NNODE];
    t[b*FCIN + j] = v;
  } else {                                        // ---- x0 = mean(x,-1): one wave/row
    int lane = threadIdx.x & 63, wv = threadIdx.x >> 6;
    int n = (blk - eb - TRB - DEMOB)*4 + wv;
    const float* r = x + (size_t)n*FIN;
    float2 v = *reinterpret_cast<const float2*>(r + lane*2);
    float s = v.x + v.y;
    #pragma unroll
    for(int off=1; off<64; off<<=1) s += __shfl_xor(s, off);
    if(lane == 0) x0r[n] = s * (1.0f/FIN);
  }
}

// ---------- bf16 MFMA GEMM + fused attention coefficients (r2-measured body) ----------
template<int AF32>
__global__ __launch_bounds__(256) void k_gemm_bf(const void* __restrict__ Av,
                                                 const unsigned short* __restrict__ Bt,
                                                 unsigned short* __restrict__ C,
                                                 const float* __restrict__ attS,
                                                 const float* __restrict__ attD,
                                                 float* __restrict__ a_s,
                                                 float* __restrict__ a_d,
                                                 int M, int K){
  const unsigned short* A = (const unsigned short*)Av;
  const float*         Af = (const float*)Av;
  __shared__ unsigned short As[128][LPITCH];
  __shared__ unsigned short Bs[128][LPITCH];
  int tid = threadIdx.x;
  int lane = tid & 63, wv = tid >> 6;
  int wm = (wv & 1)*64, wn = (wv >> 1)*64;
  int m0 = blockIdx.y*128, n0 = blockIdx.x*128;
  int l15 = lane & 15, lq = lane >> 4;
  f32x4 acc[4][4];
  #pragma unroll
  for(int i=0;i<4;i++)
    #pragma unroll
    for(int j=0;j<4;j++)
      acc[i][j] = (f32x4){0.f,0.f,0.f,0.f};

  int r = tid >> 2, c = (tid & 3)*8;
  for(int k0 = 0; k0 < K; k0 += BK){
    if(AF32){
      const float* pa  = Af + (size_t)(m0+r)*K + k0 + c;
      const float* pa2 = Af + (size_t)(m0+r+64)*K + k0 + c;
      float4 u0 = ld4(pa),  u1 = ld4(pa+4);
      float4 v0 = ld4(pa2), v1 = ld4(pa2+4);
      uint4 w0, w1;
      w0.x = pk2bf(u0.x,u0.y); w0.y = pk2bf(u0.z,u0.w);
      w0.z = pk2bf(u1.x,u1.y); w0.w = pk2bf(u1.z,u1.w);
      w1.x = pk2bf(v0.x,v0.y); w1.y = pk2bf(v0.z,v0.w);
      w1.z = pk2bf(v1.x,v1.y); w1.w = pk2bf(v1.z,v1.w);
      *reinterpret_cast<uint4*>(&As[r][c])    = w0;
      *reinterpret_cast<uint4*>(&As[r+64][c]) = w1;
    } else {
      *reinterpret_cast<uint4*>(&As[r][c])    = *reinterpret_cast<const uint4*>(A  + (size_t)(m0+r)*K + k0 + c);
      *reinterpret_cast<uint4*>(&As[r+64][c]) = *reinterpret_cast<const uint4*>(A  + (size_t)(m0+r+64)*K + k0 + c);
    }
    *reinterpret_cast<uint4*>(&Bs[r][c])    = *reinterpret_cast<const uint4*>(Bt + (size_t)(n0+r)*K + k0 + c);
    *reinterpret_cast<uint4*>(&Bs[r+64][c]) = *reinterpret_cast<const uint4*>(Bt + (size_t)(n0+r+64)*K + k0 + c);
    __syncthreads();
    bf16x8 af[4], bfr[4];
    #pragma unroll
    for(int i=0;i<4;i++){
      af[i]  = *reinterpret_cast<const bf16x8*>(&As[wm + i*16 + l15][lq*8]);
      bfr[i] = *reinterpret_cast<const bf16x8*>(&Bs[wn + i*16 + l15][lq*8]);
    }
    #pragma unroll
    for(int mi=0;mi<4;mi++)
      #pragma unroll
      for(int ni=0;ni<4;ni++)
        acc[mi][ni] = __builtin_amdgcn_mfma_f32_16x16x32_bf16(af[mi], bfr[ni], acc[mi][ni], 0, 0, 0);
    __syncthreads();
  }
  // C/D layout: col = lane&15, row = (lane>>4)*4 + reg
  #pragma unroll
  for(int mi=0;mi<4;mi++){
    #pragma unroll
    for(int ni=0;ni<4;ni++){
      int cn = n0 + wn + ni*16 + l15;
      #pragma unroll
      for(int rg=0;rg<4;rg++){
        int rm = m0 + wm + mi*16 + lq*4 + rg;
        C[(size_t)rm*HCDIM + cn] = f2bf(acc[mi][ni][rg]);
      }
    }
  }
  // fused attention coefficients: this wave's 64 cols = head (n0+wn)/64
  int head = (n0 + wn) >> 6;
  float avs[4], avd[4];
  #pragma unroll
  for(int ni=0;ni<4;ni++){
    int cc = ni*16 + l15;
    avs[ni] = attS[head*64 + cc];
    avd[ni] = attD[head*64 + cc];
  }
  #pragma unroll
  for(int mi=0;mi<4;mi++){
    #pragma unroll
    for(int rg=0;rg<4;rg++){
      float ps = 0.f, pd = 0.f;
      #pragma unroll
      for(int ni=0;ni<4;ni++){
        float v = acc[mi][ni][rg];
        ps = fmaf(avs[ni], v, ps);
        pd = fmaf(avd[ni], v, pd);
      }
      #pragma unroll
      for(int off=1; off<16; off<<=1){
        ps += __shfl_xor(ps, off);
        pd += __shfl_xor(pd, off);
      }
      if(l15 == 0){
        int rm = m0 + wm + mi*16 + lq*4 + rg;
        a_s[rm*4 + head] = ps;
        a_d[rm*4 + head] = pd;
      }
    }
  }
}

// ---------- fused softmax + aggregation + bias + relu + pool-dot (r2-measured body) ----------
template<int STORE>
__global__ __launch_bounds__(256) void k_agg(const unsigned short* __restrict__ hpre,
                                             const float* __restrict__ a_s,
                                             const float* __restrict__ a_d,
                                             const int* __restrict__ cnt,
                                             const int* __restrict__ col,
                                             const float* __restrict__ bias,
                                             const float* __restrict__ pw,
                                             const float* __restrict__ pb,
                                             unsigned short* __restrict__ hout,
                                             float* __restrict__ xraw,
                                             const float* __restrict__ lnsrc,
                                             const float* __restrict__ lnw,
                                             const float* __restrict__ lnb,
                                             float* __restrict__ out,
                                             float* __restrict__ t,
                                             int which){
  __shared__ float4 ew[4][CAP];
  __shared__ int    cols[4][CAP];
  __shared__ float  lred[8];
  int bx = blockIdx.x;
  if(bx < 16){                                    // ---- piggybacked layernorm
    int b = bx;
    ln_impl(lnsrc + b*NNODE, lnw, lnb,
            out + 16 + which*(NB*NNODE) + b*NNODE,
            out + 16 + 3*(NB*NNODE) + b*(3*NNODE) + which*NNODE,
            t + b*FCIN + 3*NNODE + which*NNODE, lred);
    return;
  }
  int tid = threadIdx.x;
  int lane = tid & 63, wv = tid >> 6;
  // swizzle: graph g on XCD g%8 so its ~1MB of bf16 hpre rows stays L2-resident
  int blk  = bx - 16;
  int xcd  = blk & 7;
  int slot = blk >> 3;
  int half = slot / 500;
  int g    = xcd + 8*half;
  int n    = g*NNODE + (slot - half*500)*4 + wv;
  int f0 = lane*4;
  int hl = lane >> 4;
  float4 ad   = ld4(a_d + n*4);
  float4 asn  = ld4(a_s + n*4);
  float4 eself = exp4u(leaky4(add4(asn, ad)));   // unnormalized self weight
  int deg = min(cnt[n], CAP);
  int base = n << 6;
  if(lane < deg){
    int s = col[base + lane];
    cols[wv][lane] = s;
    ew[wv][lane] = exp4u(leaky4(add4(ld4(a_s + s*4), ad)));
  }
  float es = selh(eself, hl);
  float dsum = es;
  float4 hv = ldbf4(hpre + (size_t)n*HCDIM + f0);
  float4 acc = make_float4(es*hv.x, es*hv.y, es*hv.z, es*hv.w);
  const float* ewf = (const float*)&ew[wv][0];
  const int*   cwf = &cols[wv][0];
  for(int e = 0; e < deg; e++){
    int s = cwf[e];                       // LDS broadcast (wave-uniform)
    float w = ewf[e*4 + hl];
    dsum += w;
    float4 h2 = ldbf4(hpre + (size_t)s*HCDIM + f0);
    acc.x = fmaf(w, h2.x, acc.x); acc.y = fmaf(w, h2.y, acc.y);
    acc.z = fmaf(w, h2.z, acc.z); acc.w = fmaf(w, h2.w, acc.w);
  }
  float invh = 1.0f / (dsum + 1e-16f);
  float4 b4 = ld4(bias + f0);
  acc = make_float4(fmaxf(fmaf(acc.x,invh,b4.x),0.f), fmaxf(fmaf(acc.y,invh,b4.y),0.f),
                    fmaxf(fmaf(acc.z,invh,b4.z),0.f), fmaxf(fmaf(acc.w,invh,b4.w),0.f));
  if(STORE){
    ushort4 hb = make_ushort4(f2bf(acc.x), f2bf(acc.y), f2bf(acc.z), f2bf(acc.w));
    *reinterpret_cast<ushort4*>(hout + (size_t)n*HCDIM + f0) = hb;
  }
  float part = dot4(acc, ld4(pw + f0));
  #pragma unroll
  for(int off=1; off<64; off<<=1) part += __shfl_xor(part, off);
  if(lane == 0) xraw[n] = part + pb[0];
}

// ---------- layernorm of x2 ----------
__global__ __launch_bounds__(256) void k_lnx2(const float* __restrict__ x2r,
                                              const float* __restrict__ lnw,
                                              const float* __restrict__ lnb,
                                              float* __restrict__ out,
                                              float* __restrict__ t){
  __shared__ float red[8];
  int b = blockIdx.x;
  ln_impl(x2r + b*NNODE, lnw, lnb,
          out + 16 + 2*(NB*NNODE) + b*NNODE,
          out + 16 + 3*(NB*NNODE) + b*(3*NNODE) + 2*NNODE,
          t + b*FCIN + 3*NNODE + 2*NNODE, red);
}

// ---------- FC1 split-K, column-per-thread: 16 SCALAR accumulators (r7-measured) ----------
__global__ __launch_bounds__(256) void k_fc1(const float* __restrict__ t,
                                             const float* __restrict__ fw1,
                                             float* __restrict__ partial){
  __shared__ float ts[NB][KCC];
  int blk = blockIdx.x;
  int chunk = blk >> 1;
  int halfc = blk & 1;
  int tid = threadIdx.x;
  int k0 = chunk * KCC;
  for(int i = tid; i < NB*KCC; i += 256){
    int b = i / KCC, kk = i - b*KCC;
    ts[b][kk] = t[b*FCIN + k0 + kk];
  }
  __syncthreads();
  int j = halfc*256 + tid;
  float acc[NB];
  #pragma unroll
  for(int b=0;b<NB;b++) acc[b] = 0.f;
  const float* wp = fw1 + (size_t)k0*FC1DIM + j;
  #pragma unroll 8
  for(int kk = 0; kk < KCC; kk++){
    float w = wp[(size_t)kk*FC1DIM];
    #pragma unroll
    for(int b=0;b<NB;b++) acc[b] = fmaf(ts[b][kk], w, acc[b]);
  }
  float* po = partial + (size_t)chunk*(NB*FC1DIM) + j;
  #pragma unroll
  for(int b=0;b<NB;b++) po[b*FC1DIM] = acc[b];
}

// ---------- fc1 partial reduce: 128 blocks, 4 wave-groups over 250 chunks (r7) ----------
__global__ __launch_bounds__(256) void k_fc1r(const float* __restrict__ partial,
                                              const float* __restrict__ fb1,
                                              float* __restrict__ t1){
  __shared__ float red[3][64];
  int tid = threadIdx.x;
  int e = blockIdx.x*64 + (tid & 63);
  int g = tid >> 6;
  int c0 = (g < 2) ? g*63 : 126 + (g-2)*62;
  int cn = (g < 2) ? 63 : 62;
  float s = 0.f;
  for(int c = c0; c < c0 + cn; c++) s += partial[(size_t)c*(NB*FC1DIM) + e];
  if(g) red[g-1][tid & 63] = s;
  __syncthreads();
  if(g == 0){
    s += red[0][tid & 63] + red[1][tid & 63] + red[2][tid & 63];
    s += fb1[e & (FC1DIM-1)];
    t1[e] = fmaxf(s, 0.f);
  }
}

// ---------- fc2 + relu + fc3 fused: one block per batch (r2-measured) ----------
__global__ __launch_bounds__(128) void k_head2(const float* __restrict__ t1,
                                               const float* __restrict__ fw2,
                                               const float* __restrict__ fb2,
                                               const float* __restrict__ fw3,
                                               const float* __restrict__ fb3,
                                               float* __restrict__ pred){
  __shared__ float red[2];
  int b = blockIdx.x, j = threadIdx.x;
  const float* tr = t1 + b*FC1DIM;
  float s = fb2[j];
  for(int k=0;k<FC1DIM;k++) s = fmaf(tr[k], fw2[k*FC2DIM+j], s);
  s = fmaxf(s, 0.f) * fw3[j];
  #pragma unroll
  for(int off=1; off<64; off<<=1) s += __shfl_xor(s, off);
  int lane = j & 63, wv = j >> 6;
  if(lane == 0) red[wv] = s;
  __syncthreads();
  if(j == 0) pred[b] = red[0] + red[1] + fb3[0];
}

extern "C" void kernel_launch(void* const* d_in, const int* in_sizes, int n_in,
                              void* d_out, int out_size, void* d_ws, size_t ws_size,
                              hipStream_t stream) {
  const float* x       = (const float*)d_in[0];
  const float* W1      = (const float*)d_in[1];
  const float* attS1   = (const float*)d_in[2];
  const float* attD1   = (const float*)d_in[3];
  const float* b1      = (const float*)d_in[4];
  const float* W2      = (const float*)d_in[5];
  const float* attS2   = (const float*)d_in[6];
  const float* attD2   = (const float*)d_in[7];
  const float* b2      = (const float*)d_in[8];
  const float* pw1     = (const float*)d_in[9];
  const float* pb1     = (const float*)d_in[10];
  const float* pw2     = (const float*)d_in[11];
  const float* pb2     = (const float*)d_in[12];
  const float* lnw     = (const float*)d_in[13];
  const float* lnb     = (const float*)d_in[14];
  const float* sexemb  = (const float*)d_in[15];
  const float* mutemb  = (const float*)d_in[16];
  const float* agew    = (const float*)d_in[17];
  const float* ageb    = (const float*)d_in[18];
  const float* fw1     = (const float*)d_in[19];
  const float* fb1     = (const float*)d_in[20];
  const float* fw2     = (const float*)d_in[21];
  const float* fb2     = (const float*)d_in[22];
  const float* fw3     = (const float*)d_in[23];
  const float* fb3     = (const float*)d_in[24];
  const float* age     = (const float*)d_in[25];
  const int*   eidx    = (const int*)d_in[26];
  const int*   sex     = (const int*)d_in[27];
  const int*   mut     = (const int*)d_in[28];
  const int E0 = in_sizes[26] / 2;
  const int* esrc = eidx;
  const int* edst = eidx + E0;

  float* out = (float*)d_out;

  // workspace layout (floats first, then bf16/int)
  float* w = (float*)d_ws;
  float* a_s  = w;                        // NTOT*NH
  float* a_d  = a_s + NTOT*NH;
  float* x0r  = a_d + NTOT*NH;            // NTOT (x0r/x1r/x2r contiguous)
  float* x1r  = x0r + NTOT;
  float* x2r  = x1r + NTOT;
  float* tbuf = x2r + NTOT;               // NB*FCIN
  float* part = tbuf + NB*FCIN;           // NCH*NB*FC1DIM (250 chunks)
  float* t1   = part + (size_t)256*NB*FC1DIM;  // NB*FC1DIM
  unsigned short* hA  = (unsigned short*)(t1 + NB*FC1DIM);  // NTOT*HCDIM bf16
  unsigned short* hB  = hA  + (size_t)NTOT*HCDIM;           // NTOT*HCDIM bf16
  unsigned short* W1t = hB  + (size_t)NTOT*HCDIM;           // HCDIM*FIN bf16
  unsigned short* W2t = W1t + HCDIM*FIN;                    // HCDIM*HCDIM bf16
  int* cnt    = (int*)(W2t + HCDIM*HCDIM);   // NTOT
  int* col    = cnt + NTOT;                  // NTOT*CAP
  (void)ws_size; (void)n_in; (void)out_size;

  const int eb = (E0 + 255)/256;

  // cnt zero, then misc (build | transposes | demo | x row-means)
  k_zero<<<(NTOT+255)/256, 256, 0, stream>>>(cnt);
  k_misc<<<eb + TRB + DEMOB + NTOT/4, 256, 0, stream>>>(esrc, edst, cnt, col, E0, eb,
                                               W1, W2, W1t, W2t,
                                               sexemb, mutemb, agew, ageb,
                                               age, sex, mut, tbuf, x, x0r);

  // GAT layer 1 (attn fused into GEMM epilogue; f32 A staged+converted in-register)
  k_gemm_bf<1><<<dim3(HCDIM/128, NTOT/128), 256, 0, stream>>>(x, W1t, hA, attS1, attD1, a_s, a_d, NTOT, FIN);
  k_agg<1><<<16 + NTOT/4, 256, 0, stream>>>(hA, a_s, a_d, cnt, col, b1, pw1, pb1, hB, x1r,
                                            x0r, lnw, lnb, out, tbuf, 0);

  // GAT layer 2 (ln(x1) piggybacked on agg blocks 0..15)
  k_gemm_bf<0><<<dim3(HCDIM/128, NTOT/128), 256, 0, stream>>>(hB, W2t, hA, attS2, attD2, a_s, a_d, NTOT, HCDIM);
  k_agg<0><<<16 + NTOT/4, 256, 0, stream>>>(hA, a_s, a_d, cnt, col, b2, pw2, pb2, hB, x2r,
                                            x1r, lnw, lnb, out, tbuf, 1);

  // remaining tail: ln(x2) only
  k_lnx2<<<NB, 256, 0, stream>>>(x2r, lnw, lnb, out, tbuf);

  // FC head: scalar-acc split-K fc1 -> wide parallel reduce -> tiny fc2/fc3
  k_fc1<<<NCH*2, 256, 0, stream>>>(tbuf, fw1, part);
  k_fc1r<<<(NB*FC1DIM)/64, 256, 0, stream>>>(part, fb1, t1);
  k_head2<<<NB, 128, 0, stream>>>(t1, fw2, fb2, fw3, fb3, out);
}